// Round 5
// baseline (13.177 us; speedup 1.0000x reference)
//
#include <hip/hip_runtime.h>
#include <hip/hip_bf16.h>

typedef float floatx4 __attribute__((ext_vector_type(4)));

// ---------------------------------------------------------------------------
// Single fused kernel, barrier-free.
//
// Analytic circuit constants (Heisenberg pullback of Z through the CNOT ring
// over the RX product state):
//   attn_vec[0] = prod_{j=1..7} cos(rx[j]);  attn_vec[k] = prod_{j=0..k} cos(rx[j])
//   ffn_vec[q]  = cos(ry[q])
//   attn_out = attn_vec @ Wc^T + bc
//   ffn_out  = W2 @ relu(W1 @ ffn_vec + b1) + b2
//
// Every WAVE computes the constants redundantly in registers (butterfly
// shfl_xor reduce -> all lanes hold the result; no LDS, no __syncthreads).
// Each thread streams 4 rows; all 8 float4 loads are issued BEFORE the
// prologue so the constant math hides under HBM latency. 512 blocks are all
// co-resident (2/CU) so the full 33.5 MB of traffic is in flight at once.
// ---------------------------------------------------------------------------
__global__ void __launch_bounds__(256) fused_all_kernel(
    const float* __restrict__ x,
    const float* __restrict__ rx, const float* __restrict__ ry,
    const float* __restrict__ Wc, const float* __restrict__ bc,
    const float* __restrict__ W1, const float* __restrict__ b1,
    const float* __restrict__ W2, const float* __restrict__ b2,
    const float* __restrict__ ln1w, const float* __restrict__ ln1b,
    const float* __restrict__ ln2w, const float* __restrict__ ln2b,
    float* __restrict__ out, int nrows)
{
    const int t = threadIdx.x;
    const int lane = t & 63;
    const int gsize = gridDim.x * 256;
    const int tid = blockIdx.x * 256 + t;

    // ---- issue all streaming loads first (consumed after the prologue) ----
    int rows[4];
    floatx4 xv[4][2];
#pragma unroll
    for (int i = 0; i < 4; ++i) {
        rows[i] = tid + i * gsize;
        if (rows[i] < nrows) {
            const floatx4* p = reinterpret_cast<const floatx4*>(x + (size_t)rows[i] * 8);
            xv[i][0] = p[0];
            xv[i][1] = p[1];
        } else {
            xv[i][0] = (floatx4){0, 0, 0, 0};
            xv[i][1] = (floatx4){0, 0, 0, 0};
        }
    }

    // ---- constant prologue (per-wave, register-only) ----
    float ca[8];
#pragma unroll
    for (int q = 0; q < 8; ++q) ca[q] = __cosf(rx[q]);
    float attv[8];
    attv[0] = ca[1] * ca[2] * ca[3] * ca[4] * ca[5] * ca[6] * ca[7];
    {
        float p = ca[0];
#pragma unroll
        for (int k = 1; k < 8; ++k) { p *= ca[k]; attv[k] = p; }
    }
    float fz[8];
#pragma unroll
    for (int q = 0; q < 8; ++q) fz[q] = __cosf(ry[q]);

    // MLP: lane owns hidden units f = lane + 64*i, i = 0..7 (full 512 per wave)
    float acc[8] = {0, 0, 0, 0, 0, 0, 0, 0};
#pragma unroll
    for (int i = 0; i < 8; ++i) {
        const int f = lane + 64 * i;
        float hv = b1[f];
#pragma unroll
        for (int q = 0; q < 8; ++q) hv = fmaf(fz[q], W1[f * 8 + q], hv);
        hv = fmaxf(hv, 0.0f);
#pragma unroll
        for (int d = 0; d < 8; ++d) acc[d] = fmaf(hv, W2[d * 512 + f], acc[d]);
    }
    // butterfly: every lane ends with the full sum
#pragma unroll
    for (int off = 32; off >= 1; off >>= 1)
#pragma unroll
        for (int d = 0; d < 8; ++d)
            acc[d] += __shfl_xor(acc[d], off);

    float att[8], ffn[8], w1[8], b1v[8], w2[8], b2v[8];
#pragma unroll
    for (int d = 0; d < 8; ++d) {
        float a = bc[d];
#pragma unroll
        for (int q = 0; q < 8; ++q) a = fmaf(attv[q], Wc[d * 8 + q], a);
        att[d] = a;
        ffn[d] = acc[d] + b2[d];
        w1[d] = ln1w[d]; b1v[d] = ln1b[d];
        w2[d] = ln2w[d]; b2v[d] = ln2b[d];
    }

    // ---- row math: add + LN1 + add + LN2 ----
    auto process = [&](floatx4 v0, floatx4 v1, floatx4& o0, floatx4& o1) {
        float h[8] = {v0.x, v0.y, v0.z, v0.w, v1.x, v1.y, v1.z, v1.w};
        float m = 0.0f;
#pragma unroll
        for (int j = 0; j < 8; ++j) { h[j] += att[j]; m += h[j]; }
        m *= 0.125f;
        float v = 0.0f;
#pragma unroll
        for (int j = 0; j < 8; ++j) { const float d = h[j] - m; v = fmaf(d, d, v); }
        v *= 0.125f;
        const float r1 = rsqrtf(v + 1e-5f);

        float g[8];
        float m2 = 0.0f;
#pragma unroll
        for (int j = 0; j < 8; ++j) {
            g[j] = fmaf((h[j] - m) * r1, w1[j], b1v[j]) + ffn[j];
            m2 += g[j];
        }
        m2 *= 0.125f;
        float v2 = 0.0f;
#pragma unroll
        for (int j = 0; j < 8; ++j) { const float d = g[j] - m2; v2 = fmaf(d, d, v2); }
        v2 *= 0.125f;
        const float r2 = rsqrtf(v2 + 1e-5f);

        o0.x = fmaf((g[0] - m2) * r2, w2[0], b2v[0]);
        o0.y = fmaf((g[1] - m2) * r2, w2[1], b2v[1]);
        o0.z = fmaf((g[2] - m2) * r2, w2[2], b2v[2]);
        o0.w = fmaf((g[3] - m2) * r2, w2[3], b2v[3]);
        o1.x = fmaf((g[4] - m2) * r2, w2[4], b2v[4]);
        o1.y = fmaf((g[5] - m2) * r2, w2[5], b2v[5]);
        o1.z = fmaf((g[6] - m2) * r2, w2[6], b2v[6]);
        o1.w = fmaf((g[7] - m2) * r2, w2[7], b2v[7]);
    };

#pragma unroll
    for (int i = 0; i < 4; ++i) {
        if (rows[i] < nrows) {
            floatx4 o0, o1;
            process(xv[i][0], xv[i][1], o0, o1);
            floatx4* op = reinterpret_cast<floatx4*>(out + (size_t)rows[i] * 8);
            __builtin_nontemporal_store(o0, op);
            __builtin_nontemporal_store(o1, op + 1);
        }
    }
}

extern "C" void kernel_launch(void* const* d_in, const int* in_sizes, int n_in,
                              void* d_out, int out_size, void* d_ws, size_t ws_size,
                              hipStream_t stream) {
    const float* x   = (const float*)d_in[0];
    const float* rx  = (const float*)d_in[1];
    const float* ry  = (const float*)d_in[2];
    const float* Wc  = (const float*)d_in[3];
    const float* bc  = (const float*)d_in[4];
    const float* W1  = (const float*)d_in[5];
    const float* b1  = (const float*)d_in[6];
    const float* W2  = (const float*)d_in[7];
    const float* b2  = (const float*)d_in[8];
    const float* ln1w = (const float*)d_in[9];
    const float* ln1b = (const float*)d_in[10];
    const float* ln2w = (const float*)d_in[11];
    const float* ln2b = (const float*)d_in[12];
    float* out = (float*)d_out;

    const int nrows = in_sizes[0] / 8;            // B*S = 524288
    const int blocks = (nrows + 4 * 256 - 1) / (4 * 256);  // 512

    fused_all_kernel<<<blocks, 256, 0, stream>>>(
        x, rx, ry, Wc, bc, W1, b1, W2, b2,
        ln1w, ln1b, ln2w, ln2b, out, nrows);
}